// Round 1
// baseline (606.586 us; speedup 1.0000x reference)
//
#include <hip/hip_runtime.h>

// ---------------------------------------------------------------------------
// MultiHeadSelfAttention: x[4,2048,768] -> (out[4,2048,768], att[4,12,2048,2048])
// Pipeline: cvt/transpose -> QKV GEMM (bf16 MFMA) -> fused attention -> proj GEMM
// ---------------------------------------------------------------------------

typedef __attribute__((ext_vector_type(8))) short          bf16x8;   // 8 bf16 (4 VGPR)
typedef __attribute__((ext_vector_type(4))) float          f32x4;
typedef __attribute__((ext_vector_type(4))) unsigned short us4;

#define DEVFN static __device__ __forceinline__

enum : int { Bb = 4, Nn = 2048, Cc = 768, Hh = 12, Dd = 64, BH = 48, Mm = 8192, C3 = 2304 };

DEVFN unsigned short f2bf(float f) {
    unsigned int u = __float_as_uint(f);
    u = (u + 0x7fffu + ((u >> 16) & 1u)) >> 16;   // RNE
    return (unsigned short)u;
}

DEVFN void gload16(void* lds, const void* g) {
    // async global->LDS, 16B per lane; LDS dest = wave-uniform base + lane*16
    __builtin_amdgcn_global_load_lds(
        (__attribute__((address_space(1))) void*)(g),
        (__attribute__((address_space(3))) void*)(lds), 16, 0, 0);
}

DEVFN f32x4 mfma_bf16(bf16x8 a, bf16x8 b, f32x4 c) {
    return __builtin_amdgcn_mfma_f32_16x16x32_bf16(a, b, c, 0, 0, 0);
}

// ---------------------------------------------------------------- cvt x->bf16
__global__ __launch_bounds__(256) void k_cvt_bf16(const float* __restrict__ in,
                                                  unsigned short* __restrict__ out, int n4) {
    int i = blockIdx.x * 256 + threadIdx.x;
    if (i < n4) {
        f32x4 v = ((const f32x4*)in)[i];
        us4 o;
        o[0] = f2bf(v[0]); o[1] = f2bf(v[1]); o[2] = f2bf(v[2]); o[3] = f2bf(v[3]);
        ((us4*)out)[i] = o;
    }
}

// ------------------------------------------------- transpose f32[R][C] -> bf16[C][R]
__global__ __launch_bounds__(256) void k_transpose_bf16(const float* __restrict__ in,
                                                        unsigned short* __restrict__ out,
                                                        int R, int Ccols) {
    __shared__ float t[64][65];
    int r0 = blockIdx.x * 64, c0 = blockIdx.y * 64;
    int tid = threadIdx.x;
#pragma unroll
    for (int i = 0; i < 16; i++) {
        int idx = i * 256 + tid; int lr = idx >> 6, lc = idx & 63;
        t[lr][lc] = in[(size_t)(r0 + lr) * Ccols + c0 + lc];
    }
    __syncthreads();
#pragma unroll
    for (int i = 0; i < 16; i++) {
        int idx = i * 256 + tid; int lc = idx >> 6, lr = idx & 63;
        out[(size_t)(c0 + lc) * R + r0 + lr] = f2bf(t[lr][lc]);
    }
}

// ------------------------------------------------------------- QKV GEMM
// A = xb [8192][768] bf16,  Bt = wqkvt [2304][768] bf16 (row = output col, contraction-contig)
// epilogue scatters: q (scaled 0.125) -> qO[bh][tok][64], k -> kO[bh][tok][64], v -> vT[bh][64][tok]
__global__ __launch_bounds__(256) void k_gemm_qkv(const unsigned short* __restrict__ A,
                                                  const unsigned short* __restrict__ Bt,
                                                  const float* __restrict__ bias,
                                                  unsigned short* __restrict__ qO,
                                                  unsigned short* __restrict__ kO,
                                                  unsigned short* __restrict__ vT) {
    __shared__ __align__(16) unsigned short As[128 * 64];
    __shared__ __align__(16) unsigned short Bs[128 * 64];
    char* AsB = (char*)As; char* BsB = (char*)Bs;
    int tid = threadIdx.x, lane = tid & 63, w = tid >> 6;
    int l15 = lane & 15, g = lane >> 4;
    int m0 = blockIdx.x * 128, n0 = blockIdx.y * 128;
    int wr = w >> 1, wc = w & 1;
    f32x4 acc[4][4] = {};

    for (int ks = 0; ks < 768; ks += 64) {
        __syncthreads();
#pragma unroll
        for (int i = 0; i < 4; i++) {
            int chunk = i * 256 + tid;
            int row = chunk >> 3, c8 = chunk & 7;
            gload16(AsB + chunk * 16, A + (size_t)(m0 + row) * 768 + ks + c8 * 8);
            gload16(BsB + chunk * 16, Bt + (size_t)(n0 + row) * 768 + ks + c8 * 8);
        }
        __syncthreads();
#pragma unroll
        for (int j = 0; j < 2; j++) {
            bf16x8 af[4], bf[4];
#pragma unroll
            for (int mb = 0; mb < 4; mb++) {
                int m = wr * 64 + mb * 16 + l15;
                af[mb] = *(const bf16x8*)(AsB + m * 128 + j * 64 + g * 16);
            }
#pragma unroll
            for (int nb = 0; nb < 4; nb++) {
                int n = wc * 64 + nb * 16 + l15;
                bf[nb] = *(const bf16x8*)(BsB + n * 128 + j * 64 + g * 16);
            }
#pragma unroll
            for (int mb = 0; mb < 4; mb++)
#pragma unroll
                for (int nb = 0; nb < 4; nb++)
                    acc[mb][nb] = mfma_bf16(af[mb], bf[nb], acc[mb][nb]);
        }
    }

    int which = n0 / 768;  // uniform per block (768 = 6*128)
#pragma unroll
    for (int nb = 0; nb < 4; nb++) {
        int n_g = n0 + wc * 64 + nb * 16 + l15;
        float bs = bias[n_g];
        int h = (n_g - which * 768) >> 6, d = n_g & 63;
#pragma unroll
        for (int mb = 0; mb < 4; mb++) {
            f32x4 v = acc[mb][nb];
#pragma unroll
            for (int r = 0; r < 4; r++) {
                int m_g = m0 + wr * 64 + mb * 16 + g * 4 + r;
                int bI = m_g >> 11, tok = m_g & 2047;
                int bh = bI * 12 + h;
                float val = v[r] + bs;
                if (which == 0)
                    qO[(size_t)(bh * 2048 + tok) * 64 + d] = f2bf(val * 0.125f); // fold D^-0.5
                else if (which == 1)
                    kO[(size_t)(bh * 2048 + tok) * 64 + d] = f2bf(val);
                else
                    vT[(size_t)(bh * 64 + d) * 2048 + tok] = f2bf(val);
            }
        }
    }
}

// ------------------------------------------------------------- fused attention
// grid (64 q-tiles, 48 bh); 512 threads = 8 waves; per WG: 32 q-rows, full 2048 keys.
// pass1: online (max,sum) over 64-key tiles. pass2: recompute S, write att f32, bounce
// att(bf16) through 4KB swizzled LDS tile, PV MFMA -> ctx bf16 [b][q][h*64+d].
__global__ __launch_bounds__(512) void k_attn(const unsigned short* __restrict__ qb,
                                              const unsigned short* __restrict__ kbuf,
                                              const unsigned short* __restrict__ vT,
                                              const int* __restrict__ mask,
                                              const float* __restrict__ pbias,
                                              float* __restrict__ attO,
                                              unsigned short* __restrict__ ctx) {
    __shared__ __align__(16) char smem[21760];
    char* Ks  = smem;          // [64 key][128B], chunk-XOR swizzled by (key&7)
    char* Vs  = smem + 8192;   // [64 d][128B] of V^T, chunk-XOR swizzled by (d&7)
    char* Ssm = smem + 16384;  // att bf16 [32 q][128B], chunk-XOR swizzled by (row&7)
    float* m_part = (float*)(smem + 20480);   // [4][32]
    float* l_part = (float*)(smem + 20992);   // [4][32]
    float* rowmax = (float*)(smem + 21504);   // [32]
    float* rowinv = (float*)(smem + 21632);   // [32]

    int tid = threadIdx.x, lane = tid & 63, w = tid >> 6;
    int l15 = lane & 15, g = lane >> 4;
    int qt = blockIdx.x, bh = blockIdx.y, b = bh / 12, h = bh - b * 12;
    int q0 = qt * 32;
    int rb = w >> 2, cb = w & 3;
    float pbh = pbias[h];

    const unsigned short* kbase = kbuf + (size_t)bh * 2048 * 64;
    const unsigned short* vbase = vT + (size_t)bh * 64 * 2048;
    const int* mrow = mask + b * 2048;

    // Q fragments (rows rb*16+l15, k-dims g*8.. ; scale already folded in)
    bf16x8 qf0, qf1;
    {
        const unsigned short* qp = qb + (size_t)(bh * 2048 + q0 + rb * 16 + l15) * 64 + g * 8;
        qf0 = *(const bf16x8*)(qp);
        qf1 = *(const bf16x8*)(qp + 32);
    }

    float m_run[4], l_run[4];
#pragma unroll
    for (int r = 0; r < 4; r++) { m_run[r] = -1e30f; l_run[r] = 0.0f; }

    // ---------------- pass 1: online max / sumexp ----------------
    for (int kb = 0; kb < 32; kb++) {
        __syncthreads();
        {
            int key = tid >> 3; int c8 = (tid & 7) ^ (key & 7);
            gload16(Ks + tid * 16, kbase + (size_t)(kb * 64 + key) * 64 + c8 * 8);
        }
        __syncthreads();
        f32x4 acc = {};
        {
            int key = cb * 16 + l15;
            const char* kr = Ks + key * 128;
            bf16x8 b0 = *(const bf16x8*)(kr + ((g ^ (key & 7)) << 4));
            bf16x8 b1 = *(const bf16x8*)(kr + (((4 + g) ^ (key & 7)) << 4));
            acc = mfma_bf16(qf0, b0, acc);
            acc = mfma_bf16(qf1, b1, acc);
        }
        int colg = kb * 64 + cb * 16 + l15;
        int mv = mrow[colg];
#pragma unroll
        for (int r = 0; r < 4; r++) {
            float s = mv ? (acc[r] + pbh) : -30000.0f;
            float mt = s;
            mt = fmaxf(mt, __shfl_xor(mt, 1, 16));
            mt = fmaxf(mt, __shfl_xor(mt, 2, 16));
            mt = fmaxf(mt, __shfl_xor(mt, 4, 16));
            mt = fmaxf(mt, __shfl_xor(mt, 8, 16));
            float nm = fmaxf(m_run[r], mt);
            float e = __expf(s - nm);
            e += __shfl_xor(e, 1, 16);
            e += __shfl_xor(e, 2, 16);
            e += __shfl_xor(e, 4, 16);
            e += __shfl_xor(e, 8, 16);
            l_run[r] = l_run[r] * __expf(m_run[r] - nm) + e;
            m_run[r] = nm;
        }
    }
    if (l15 == 0) {
#pragma unroll
        for (int r = 0; r < 4; r++) {
            int row = rb * 16 + g * 4 + r;
            m_part[cb * 32 + row] = m_run[r];
            l_part[cb * 32 + row] = l_run[r];
        }
    }
    __syncthreads();
    if (tid < 32) {
        float M = m_part[tid];
        M = fmaxf(M, m_part[32 + tid]);
        M = fmaxf(M, m_part[64 + tid]);
        M = fmaxf(M, m_part[96 + tid]);
        float L = 0.0f;
#pragma unroll
        for (int c = 0; c < 4; c++) L += l_part[c * 32 + tid] * __expf(m_part[c * 32 + tid] - M);
        rowmax[tid] = M;
        rowinv[tid] = 1.0f / L;
    }

    // ---------------- pass 2: att write + PV ----------------
    f32x4 cacc = {};
    for (int kb = 0; kb < 32; kb++) {
        __syncthreads();
        {
            int key = tid >> 3; int c8 = (tid & 7) ^ (key & 7);
            gload16(Ks + tid * 16, kbase + (size_t)(kb * 64 + key) * 64 + c8 * 8);
            gload16(Vs + tid * 16, vbase + (size_t)key * 2048 + kb * 64 + c8 * 8); // key==d here
        }
        __syncthreads();
        f32x4 acc = {};
        {
            int key = cb * 16 + l15;
            const char* kr = Ks + key * 128;
            bf16x8 b0 = *(const bf16x8*)(kr + ((g ^ (key & 7)) << 4));
            bf16x8 b1 = *(const bf16x8*)(kr + (((4 + g) ^ (key & 7)) << 4));
            acc = mfma_bf16(qf0, b0, acc);
            acc = mfma_bf16(qf1, b1, acc);
        }
        int colg = kb * 64 + cb * 16 + l15;
        int mv = mrow[colg];
        int colL = cb * 16 + l15;
        int c8L = colL >> 3, lo = (colL & 7) * 2;
#pragma unroll
        for (int r = 0; r < 4; r++) {
            int row = rb * 16 + g * 4 + r;
            float s = mv ? (acc[r] + pbh) : -30000.0f;
            float a = __expf(s - rowmax[row]) * rowinv[row];
            attO[(size_t)(bh * 2048 + q0 + row) * 2048 + colg] = a;
            *(unsigned short*)(Ssm + row * 128 + ((c8L ^ (row & 7)) << 4) + lo) = f2bf(a);
        }
        __syncthreads();
        {
            int row = rb * 16 + l15;              // A rows = q
            const char* pr = Ssm + row * 128;
            bf16x8 a0 = *(const bf16x8*)(pr + ((g ^ (row & 7)) << 4));
            bf16x8 a1 = *(const bf16x8*)(pr + (((4 + g) ^ (row & 7)) << 4));
            int d = cb * 16 + l15;                // B cols = d
            const char* vr = Vs + d * 128;
            bf16x8 v0 = *(const bf16x8*)(vr + ((g ^ (d & 7)) << 4));
            bf16x8 v1 = *(const bf16x8*)(vr + (((4 + g) ^ (d & 7)) << 4));
            cacc = mfma_bf16(a0, v0, cacc);
            cacc = mfma_bf16(a1, v1, cacc);
        }
    }
    {
        int d = cb * 16 + l15;
#pragma unroll
        for (int r = 0; r < 4; r++) {
            int row = rb * 16 + g * 4 + r;
            ctx[(size_t)(b * 2048 + q0 + row) * 768 + h * 64 + d] = f2bf(cacc[r]);
        }
    }
}

// ------------------------------------------------------------- proj GEMM
__global__ __launch_bounds__(256) void k_gemm_proj(const unsigned short* __restrict__ A,
                                                   const unsigned short* __restrict__ Bt,
                                                   const float* __restrict__ bias,
                                                   float* __restrict__ out) {
    __shared__ __align__(16) unsigned short As[128 * 64];
    __shared__ __align__(16) unsigned short Bs[128 * 64];
    char* AsB = (char*)As; char* BsB = (char*)Bs;
    int tid = threadIdx.x, lane = tid & 63, w = tid >> 6;
    int l15 = lane & 15, g = lane >> 4;
    int m0 = blockIdx.x * 128, n0 = blockIdx.y * 128;
    int wr = w >> 1, wc = w & 1;
    f32x4 acc[4][4] = {};

    for (int ks = 0; ks < 768; ks += 64) {
        __syncthreads();
#pragma unroll
        for (int i = 0; i < 4; i++) {
            int chunk = i * 256 + tid;
            int row = chunk >> 3, c8 = chunk & 7;
            gload16(AsB + chunk * 16, A + (size_t)(m0 + row) * 768 + ks + c8 * 8);
            gload16(BsB + chunk * 16, Bt + (size_t)(n0 + row) * 768 + ks + c8 * 8);
        }
        __syncthreads();
#pragma unroll
        for (int j = 0; j < 2; j++) {
            bf16x8 af[4], bf[4];
#pragma unroll
            for (int mb = 0; mb < 4; mb++) {
                int m = wr * 64 + mb * 16 + l15;
                af[mb] = *(const bf16x8*)(AsB + m * 128 + j * 64 + g * 16);
            }
#pragma unroll
            for (int nb = 0; nb < 4; nb++) {
                int n = wc * 64 + nb * 16 + l15;
                bf[nb] = *(const bf16x8*)(BsB + n * 128 + j * 64 + g * 16);
            }
#pragma unroll
            for (int mb = 0; mb < 4; mb++)
#pragma unroll
                for (int nb = 0; nb < 4; nb++)
                    acc[mb][nb] = mfma_bf16(af[mb], bf[nb], acc[mb][nb]);
        }
    }
#pragma unroll
    for (int nb = 0; nb < 4; nb++) {
        int n_g = n0 + wc * 64 + nb * 16 + l15;
        float bs = bias[n_g];
#pragma unroll
        for (int mb = 0; mb < 4; mb++) {
            f32x4 v = acc[mb][nb];
#pragma unroll
            for (int r = 0; r < 4; r++) {
                int m_g = m0 + wr * 64 + mb * 16 + g * 4 + r;
                out[(size_t)m_g * 768 + n_g] = v[r] + bs;
            }
        }
    }
}

// ---------------------------------------------------------------------------
extern "C" void kernel_launch(void* const* d_in, const int* in_sizes, int n_in,
                              void* d_out, int out_size, void* d_ws, size_t ws_size,
                              hipStream_t stream) {
    (void)in_sizes; (void)n_in; (void)out_size; (void)ws_size;
    const float* x      = (const float*)d_in[0];
    const int*   mask   = (const int*)d_in[1];
    const float* w_qkv  = (const float*)d_in[2];
    const float* b_qkv  = (const float*)d_in[3];
    const float* w_proj = (const float*)d_in[4];
    const float* b_proj = (const float*)d_in[5];
    const float* pb     = (const float*)d_in[6];

    float* out  = (float*)d_out;
    float* attO = out + (size_t)Bb * Nn * Cc;   // 6,291,456

    char* ws = (char*)d_ws;
    unsigned short* xb     = (unsigned short*)(ws);             // 12,582,912 B
    unsigned short* wqkvt  = (unsigned short*)(ws + 12582912);  //  3,538,944 B
    unsigned short* wprojt = (unsigned short*)(ws + 16121856);  //  1,179,648 B
    unsigned short* qbuf   = (unsigned short*)(ws + 17301504);  // 12,582,912 B
    unsigned short* kbuf   = (unsigned short*)(ws + 29884416);  // 12,582,912 B
    unsigned short* vtb    = (unsigned short*)(ws + 42467328);  // 12,582,912 B
    unsigned short* ctx    = (unsigned short*)(ws + 55050240);  // 12,582,912 B  (total ~67.6 MB)

    k_cvt_bf16<<<6144, 256, 0, stream>>>(x, xb, 1572864);
    k_transpose_bf16<<<dim3(12, 36), 256, 0, stream>>>(w_qkv, wqkvt, 768, 2304);
    k_transpose_bf16<<<dim3(12, 12), 256, 0, stream>>>(w_proj, wprojt, 768, 768);
    k_gemm_qkv<<<dim3(64, 18), 256, 0, stream>>>(xb, wqkvt, b_qkv, qbuf, kbuf, vtb);
    k_attn<<<dim3(64, 48), 512, 0, stream>>>(qbuf, kbuf, vtb, mask, pb, attO, ctx);
    k_gemm_proj<<<dim3(64, 6), 256, 0, stream>>>(ctx, wprojt, b_proj, out);
}